// Round 2
// baseline (142.730 us; speedup 1.0000x reference)
//
#include <hip/hip_runtime.h>
#include <hip/hip_bf16.h>

#define B_N   4096
#define DIM   512
#define NCLS  100
#define MARGIN 0.1f
#define ONE_EPS (1.0f - 1e-5f)
#define K_POS (-2.885390082f)   // -2  * log2(e)
#define K_NEG (57.70780163f)    //  40 * log2(e)

typedef __attribute__((ext_vector_type(8))) short short8;   // 8 bf16 = 4 VGPRs (MFMA A/B frag)
typedef __attribute__((ext_vector_type(4))) float f32x4;    // MFMA C/D frag
typedef unsigned short ushort_t;
typedef unsigned char  uchar_t;

__device__ __forceinline__ void async_load16(const void* g, void* l) {
    __builtin_amdgcn_global_load_lds(
        (const __attribute__((address_space(1))) unsigned int*)g,
        (__attribute__((address_space(3))) unsigned int*)l,
        16, 0, 0);
}

__device__ __forceinline__ float blk_sum(float v, float* red) {
#pragma unroll
    for (int m = 32; m; m >>= 1) v += __shfl_xor(v, m, 64);
    const int w = threadIdx.x >> 6;
    if ((threadIdx.x & 63) == 0) red[w] = v;
    __syncthreads();
    v = red[0] + red[1] + red[2] + red[3];
    __syncthreads();
    return v;
}

// ---------- K1: normalize rows -> bf16, one-hot -> u8 index, zero out ----------
__global__ __launch_bounds__(256) void prep_kernel(
    const float* __restrict__ feats, const float* __restrict__ labels,
    ushort_t* __restrict__ fn, uchar_t* __restrict__ lab8, float* __restrict__ out)
{
    __shared__ float red[4];
    const int r = blockIdx.x, t = threadIdx.x;
    const float v0 = feats[(size_t)r * DIM + t];
    const float v1 = feats[(size_t)r * DIM + t + 256];
    const float ss = blk_sum(v0 * v0 + v1 * v1, red);
    const float sc = rsqrtf(ss);
    __hip_bfloat16 b0 = __float2bfloat16(v0 * sc);
    __hip_bfloat16 b1 = __float2bfloat16(v1 * sc);
    fn[(size_t)r * DIM + t]       = *(ushort_t*)&b0;
    fn[(size_t)r * DIM + t + 256] = *(ushort_t*)&b1;
    if (t < NCLS && labels[(size_t)r * NCLS + t] > 0.5f) lab8[r] = (uchar_t)t;
    if (r == 0 && t == 0) out[0] = 0.0f;
}

// ---------- K2: sim = F*F^T (bf16 out), upper-triangle tiles only ----------
#define BM 128
#define BK 32
#define NKSTEP (DIM / BK)   // 16

__global__ __launch_bounds__(256) void gemm_sim(
    const ushort_t* __restrict__ F, ushort_t* __restrict__ Cb)
{
    if (blockIdx.x < blockIdx.y) return;   // symmetric: upper triangle only
    __shared__ __align__(16) ushort_t sA[2][BM * BK];
    __shared__ __align__(16) ushort_t sB[2][BM * BK];
    const int t = threadIdx.x;
    const int w = t >> 6, l = t & 63;
    const int brow = blockIdx.y * BM, bcol = blockIdx.x * BM;
    const bool offdiag = (blockIdx.x != blockIdx.y);
    const int wr = w >> 1, wc = w & 1;          // 2x2 waves -> 64x64 each

    const int lr    = l >> 2;
    const int lslot = l & 3;

    f32x4 acc[4][4];
    const f32x4 fz = {0.f, 0.f, 0.f, 0.f};
#pragma unroll
    for (int m = 0; m < 4; ++m)
#pragma unroll
        for (int n = 0; n < 4; ++n) acc[m][n] = fz;

    auto stage = [&](int buf, int kb) {
#pragma unroll
        for (int i = 0; i < 2; ++i) {
            const int c   = w * 2 + i;
            const int row = c * 16 + lr;
            const int kc  = lslot ^ ((row >> 1) & 3);
            async_load16(F + (size_t)(brow + row) * DIM + kb + kc * 8, &sA[buf][c * 512]);
            async_load16(F + (size_t)(bcol + row) * DIM + kb + kc * 8, &sB[buf][c * 512]);
        }
    };

    stage(0, 0);
    __syncthreads();
    int cur = 0;
    for (int ks = 0; ks < NKSTEP; ++ks) {
        if (ks + 1 < NKSTEP) stage(cur ^ 1, (ks + 1) * BK);
        short8 av[4], bv[4];
#pragma unroll
        for (int m = 0; m < 4; ++m) {
            const int r    = wr * 64 + m * 16 + (l & 15);
            const int slot = (l >> 4) ^ ((r >> 1) & 3);
            av[m] = *(const short8*)&sA[cur][r * BK + slot * 8];
        }
#pragma unroll
        for (int n = 0; n < 4; ++n) {
            const int r    = wc * 64 + n * 16 + (l & 15);
            const int slot = (l >> 4) ^ ((r >> 1) & 3);
            bv[n] = *(const short8*)&sB[cur][r * BK + slot * 8];
        }
#pragma unroll
        for (int m = 0; m < 4; ++m)
#pragma unroll
            for (int n = 0; n < 4; ++n)
                acc[m][n] = __builtin_amdgcn_mfma_f32_16x16x32_bf16(av[m], bv[n], acc[m][n], 0, 0, 0);
        __syncthreads();
        cur ^= 1;
    }

    // epilogue: C/D layout col = l&15, row = (l>>4)*4 + r; mirror off-diag tiles
#pragma unroll
    for (int m = 0; m < 4; ++m) {
        const int row0 = wr * 64 + m * 16 + ((l >> 4) << 2);
#pragma unroll
        for (int n = 0; n < 4; ++n) {
            const int col = wc * 64 + n * 16 + (l & 15);
#pragma unroll
            for (int r = 0; r < 4; ++r) {
                __hip_bfloat16 hv = __float2bfloat16(acc[m][n][r]);
                const ushort_t uv = *(ushort_t*)&hv;
                const int gr = brow + row0 + r, gc = bcol + col;
                Cb[(size_t)gr * B_N + gc] = uv;
                if (offdiag) Cb[(size_t)gc * B_N + gr] = uv;
            }
        }
    }
}

// ---------- K3: per-row mining + loss, ONE WAVE per row, no syncthreads ----------
__global__ __launch_bounds__(256) void row_loss_kernel(
    const ushort_t* __restrict__ Cb, const uchar_t* __restrict__ lab8,
    float* __restrict__ out)
{
    const int w = threadIdx.x >> 6, l = threadIdx.x & 63;
    const int i = blockIdx.x * 4 + w;
    const int li = (int)lab8[i];

    // lane l holds columns j = c*512 + l*8 + e (c in [0,8), e in [0,8))
    uint4 sp[8];   // packed bf16 sim, 8 per chunk
    uint2 lp[8];   // packed u8 labels, 8 per chunk
    const uint4* cbase = (const uint4*)(Cb + (size_t)i * B_N);
    const uint2* lbase = (const uint2*)lab8;
#pragma unroll
    for (int c = 0; c < 8; ++c) {
        sp[c] = cbase[c * 64 + l];
        lp[c] = lbase[c * 64 + l];
    }

    // poison diagonal sim -> 2.0 (same-label but fails s < 1-eps; never a neg)
#pragma unroll
    for (int c = 0; c < 8; ++c) {
        const int d = i - (c * 512 + l * 8);
        if (d >= 0 && d < 8) {
            unsigned int* pw = (unsigned int*)&sp[c];
            if (d & 1) pw[d >> 1] = (pw[d >> 1] & 0x0000FFFFu) | 0x40000000u;
            else       pw[d >> 1] = (pw[d >> 1] & 0xFFFF0000u) | 0x00004000u;
        }
    }

#define UNPACK(c, e, s, lbl)                                                     \
    const unsigned int _u = ((const unsigned int*)&sp[c])[(e) >> 1];             \
    const float s = __uint_as_float(((e) & 1) ? (_u & 0xFFFF0000u) : (_u << 16));\
    const unsigned int _lw = ((e) < 4) ? lp[c].x : lp[c].y;                      \
    const int lbl = (int)((_lw >> (((e) & 3) * 8)) & 0xFFu);

    // pass 1: pos_min
    float pmin = __builtin_inff();
#pragma unroll
    for (int c = 0; c < 8; ++c)
#pragma unroll
        for (int e = 0; e < 8; ++e) {
            UNPACK(c, e, s, lbl)
            if (lbl == li && s < ONE_EPS) pmin = fminf(pmin, s);
        }
#pragma unroll
    for (int m = 32; m; m >>= 1) pmin = fminf(pmin, __shfl_xor(pmin, m, 64));

    // pass 2: neg_max + neg exp-sum (neg_keep depends only on pmin)
    float nmax = -__builtin_inff(), ns = 0.f;
    bool anyneg = false;
#pragma unroll
    for (int c = 0; c < 8; ++c)
#pragma unroll
        for (int e = 0; e < 8; ++e) {
            UNPACK(c, e, s, lbl)
            if (lbl != li && s + MARGIN > pmin) {
                nmax = fmaxf(nmax, s);
                ns += exp2f(K_NEG * (s - 0.5f));
                anyneg = true;
            }
        }
#pragma unroll
    for (int m = 32; m; m >>= 1) nmax = fmaxf(nmax, __shfl_xor(nmax, m, 64));
#pragma unroll
    for (int m = 32; m; m >>= 1) ns += __shfl_xor(ns, m, 64);

    // pass 3: pos exp-sum (pos_keep depends on nmax)
    float ps = 0.f;
    bool anypos = false;
#pragma unroll
    for (int c = 0; c < 8; ++c)
#pragma unroll
        for (int e = 0; e < 8; ++e) {
            UNPACK(c, e, s, lbl)
            if (lbl == li && s < ONE_EPS && s - MARGIN < nmax) {
                ps += exp2f(K_POS * (s - 0.5f));
                anypos = true;
            }
        }
#pragma unroll
    for (int m = 32; m; m >>= 1) ps += __shfl_xor(ps, m, 64);

    const bool valid = __any(anypos) && __any(anyneg);
    if (l == 0 && valid) {
        const float loss = log1pf(ps) * 0.5f + log1pf(ns) * 0.025f;
        atomicAdd(out, loss * (1.0f / (float)B_N));
    }
#undef UNPACK
}

extern "C" void kernel_launch(void* const* d_in, const int* in_sizes, int n_in,
                              void* d_out, int out_size, void* d_ws, size_t ws_size,
                              hipStream_t stream) {
    const float* feats  = (const float*)d_in[0];
    const float* labels = (const float*)d_in[1];
    float* out = (float*)d_out;

    // ws layout: sim bf16 [4096*4096] = 32 MB | fnorm bf16 = 4 MB | lab u8 = 4 KB
    char* ws = (char*)d_ws;
    ushort_t* Cb   = (ushort_t*)ws;
    ushort_t* fn   = (ushort_t*)(ws + (size_t)B_N * B_N * 2);
    uchar_t*  lab8 = (uchar_t*)(ws + (size_t)B_N * B_N * 2 + (size_t)B_N * DIM * 2);

    prep_kernel<<<B_N, 256, 0, stream>>>(feats, labels, fn, lab8, out);
    dim3 g2(B_N / BM, B_N / BM);
    gemm_sim<<<g2, 256, 0, stream>>>(fn, Cb);
    row_loss_kernel<<<B_N / 4, 256, 0, stream>>>(Cb, lab8, out);
}

// Round 3
// 100.063 us; speedup vs baseline: 1.4264x; 1.4264x over previous
//
#include <hip/hip_runtime.h>
#include <hip/hip_bf16.h>

#define B_N   4096
#define DIM   512
#define NCLS  100
#define MARGIN 0.1f
#define ONE_EPS (1.0f - 1e-5f)
#define K_POS (-2.885390082f)   // -2  * log2(e)
#define K_NEG (57.70780163f)    //  40 * log2(e)
#define BIGF  3.0e38f

typedef __attribute__((ext_vector_type(8))) short short8;   // 8 bf16 = 4 VGPRs (MFMA A/B frag)
typedef __attribute__((ext_vector_type(4))) float f32x4;    // MFMA C/D frag
typedef unsigned short ushort_t;
typedef unsigned char  uchar_t;

__device__ __forceinline__ void async_load16(const void* g, void* l) {
    __builtin_amdgcn_global_load_lds(
        (const __attribute__((address_space(1))) unsigned int*)g,
        (__attribute__((address_space(3))) unsigned int*)l,
        16, 0, 0);
}

__device__ __forceinline__ float blk_sum(float v, float* red) {
#pragma unroll
    for (int m = 32; m; m >>= 1) v += __shfl_xor(v, m, 64);
    const int w = threadIdx.x >> 6;
    if ((threadIdx.x & 63) == 0) red[w] = v;
    __syncthreads();
    v = red[0] + red[1] + red[2] + red[3];
    __syncthreads();
    return v;
}

// ---------- K1: normalize rows -> bf16, one-hot -> u8 index, zero out ----------
__global__ __launch_bounds__(256) void prep_kernel(
    const float* __restrict__ feats, const float* __restrict__ labels,
    ushort_t* __restrict__ fn, uchar_t* __restrict__ lab8, float* __restrict__ out)
{
    __shared__ float red[4];
    const int r = blockIdx.x, t = threadIdx.x;
    const float v0 = feats[(size_t)r * DIM + t];
    const float v1 = feats[(size_t)r * DIM + t + 256];
    const float ss = blk_sum(v0 * v0 + v1 * v1, red);
    const float sc = rsqrtf(ss);
    __hip_bfloat16 b0 = __float2bfloat16(v0 * sc);
    __hip_bfloat16 b1 = __float2bfloat16(v1 * sc);
    fn[(size_t)r * DIM + t]       = *(ushort_t*)&b0;
    fn[(size_t)r * DIM + t + 256] = *(ushort_t*)&b1;
    if (t < NCLS && labels[(size_t)r * NCLS + t] > 0.5f) lab8[r] = (uchar_t)t;
    if (r == 0 && t == 0) out[0] = 0.0f;
}

// ---------- K2: sim = F*F^T (bf16 out), full grid, m97 structure ----------
#define BM 128
#define BK 32
#define NKSTEP (DIM / BK)   // 16

__global__ __launch_bounds__(256) void gemm_sim(
    const ushort_t* __restrict__ F, ushort_t* __restrict__ Cb)
{
    __shared__ __align__(16) ushort_t sA[2][BM * BK];
    __shared__ __align__(16) ushort_t sB[2][BM * BK];
    const int t = threadIdx.x;
    const int w = t >> 6, l = t & 63;
    const int brow = blockIdx.y * BM, bcol = blockIdx.x * BM;
    const int wr = w >> 1, wc = w & 1;          // 2x2 waves -> 64x64 each

    const int lr    = l >> 2;
    const int lslot = l & 3;

    f32x4 acc[4][4];
    const f32x4 fz = {0.f, 0.f, 0.f, 0.f};
#pragma unroll
    for (int m = 0; m < 4; ++m)
#pragma unroll
        for (int n = 0; n < 4; ++n) acc[m][n] = fz;

    auto stage = [&](int buf, int kb) {
#pragma unroll
        for (int i = 0; i < 2; ++i) {
            const int c   = w * 2 + i;
            const int row = c * 16 + lr;
            const int kc  = lslot ^ ((row >> 1) & 3);
            async_load16(F + (size_t)(brow + row) * DIM + kb + kc * 8, &sA[buf][c * 512]);
            async_load16(F + (size_t)(bcol + row) * DIM + kb + kc * 8, &sB[buf][c * 512]);
        }
    };

    stage(0, 0);
    __syncthreads();
    int cur = 0;
    for (int ks = 0; ks < NKSTEP; ++ks) {
        if (ks + 1 < NKSTEP) stage(cur ^ 1, (ks + 1) * BK);
        short8 av[4], bv[4];
#pragma unroll
        for (int m = 0; m < 4; ++m) {
            const int r    = wr * 64 + m * 16 + (l & 15);
            const int slot = (l >> 4) ^ ((r >> 1) & 3);
            av[m] = *(const short8*)&sA[cur][r * BK + slot * 8];
        }
#pragma unroll
        for (int n = 0; n < 4; ++n) {
            const int r    = wc * 64 + n * 16 + (l & 15);
            const int slot = (l >> 4) ^ ((r >> 1) & 3);
            bv[n] = *(const short8*)&sB[cur][r * BK + slot * 8];
        }
#pragma unroll
        for (int m = 0; m < 4; ++m)
#pragma unroll
            for (int n = 0; n < 4; ++n)
                acc[m][n] = __builtin_amdgcn_mfma_f32_16x16x32_bf16(av[m], bv[n], acc[m][n], 0, 0, 0);
        __syncthreads();
        cur ^= 1;
    }

    // epilogue: C/D layout col = l&15, row = (l>>4)*4 + r
#pragma unroll
    for (int m = 0; m < 4; ++m) {
        const int row0 = brow + wr * 64 + m * 16 + ((l >> 4) << 2);
#pragma unroll
        for (int n = 0; n < 4; ++n) {
            const int col = bcol + wc * 64 + n * 16 + (l & 15);
            ushort_t* cp = Cb + (size_t)row0 * B_N + col;
#pragma unroll
            for (int r = 0; r < 4; ++r) {
                __hip_bfloat16 hv = __float2bfloat16(acc[m][n][r]);
                cp[(size_t)r * B_N] = *(ushort_t*)&hv;
            }
        }
    }
}

// ---------- K3: per-row mining + loss, one BLOCK per row, 2 passes ----------
__global__ __launch_bounds__(256) void row_loss_kernel(
    const ushort_t* __restrict__ Cb, const uchar_t* __restrict__ lab8,
    float* __restrict__ out)
{
    __shared__ float2 redmm[4];
    __shared__ float2 redsum[4];
    const int i = blockIdx.x, t = threadIdx.x;
    const int li = (int)lab8[i];

    // thread t owns columns j = 16*t + e, e in [0,16)
    const uint4* cb = (const uint4*)(Cb + (size_t)i * B_N);
    uint4 s0 = cb[2 * t];
    uint4 s1 = cb[2 * t + 1];
    uint4 lw = ((const uint4*)lab8)[t];

    // poison diagonal sim -> 2.0 (same-label but fails s < 1-eps; never a neg)
    if ((i >> 4) == t) {
        const int d  = i & 15;
        unsigned* wp = (d < 8) ? (unsigned*)&s0 : (unsigned*)&s1;
        const int dd = d & 7;
        if (dd & 1) wp[dd >> 1] = (wp[dd >> 1] & 0x0000FFFFu) | 0x40000000u;
        else        wp[dd >> 1] = (wp[dd >> 1] & 0xFFFF0000u) | 0x00004000u;
    }

    // pin the row data in registers (prevent per-pass reload/remat)
#define KEEP4(v) asm volatile("" : "+v"(v.x), "+v"(v.y), "+v"(v.z), "+v"(v.w))
    KEEP4(s0); KEEP4(s1); KEEP4(lw);
#undef KEEP4

    const unsigned sw[8] = {s0.x, s0.y, s0.z, s0.w, s1.x, s1.y, s1.z, s1.w};
    const unsigned lwd[4] = {lw.x, lw.y, lw.z, lw.w};

#define GET_S(e)  __uint_as_float(((e) & 1) ? (sw[(e) >> 1] & 0xFFFF0000u) : (sw[(e) >> 1] << 16))
#define GET_L(e)  ((int)((lwd[(e) >> 2] >> (((e) & 3) * 8)) & 0xFFu))

    // pass 1: pos_min (valid positives) and global neg max, together
    float pmin = BIGF, ngmax = -BIGF;
#pragma unroll
    for (int e = 0; e < 16; ++e) {
        const float s = GET_S(e);
        const int lbl = GET_L(e);
        if (lbl == li) { if (s < ONE_EPS) pmin = fminf(pmin, s); }
        else           ngmax = fmaxf(ngmax, s);
    }
#pragma unroll
    for (int m = 32; m; m >>= 1) {
        pmin  = fminf(pmin,  __shfl_xor(pmin,  m, 64));
        ngmax = fmaxf(ngmax, __shfl_xor(ngmax, m, 64));
    }
    if ((t & 63) == 0) redmm[t >> 6] = make_float2(pmin, ngmax);
    __syncthreads();
    pmin  = fminf(fminf(redmm[0].x, redmm[1].x), fminf(redmm[2].x, redmm[3].x));
    ngmax = fmaxf(fmaxf(redmm[0].y, redmm[1].y), fmaxf(redmm[2].y, redmm[3].y));

    // closed-form mining:
    //   any neg kept  <=> ngmax + margin > pmin  (then neg_max = ngmax)
    //   any pos kept  <=> pmin - margin < neg_max
    const bool anyneg = (ngmax + MARGIN > pmin);
    const float nmax  = anyneg ? ngmax : -BIGF;
    const bool valid  = anyneg && (pmin - MARGIN < nmax);
    if (!valid) return;   // uniform across block

    // pass 2: both exp-sums in one sweep
    float ps = 0.f, ns = 0.f;
#pragma unroll
    for (int e = 0; e < 16; ++e) {
        const float s = GET_S(e);
        const int lbl = GET_L(e);
        if (lbl == li) {
            if (s < ONE_EPS && s - MARGIN < nmax) ps += exp2f(K_POS * (s - 0.5f));
        } else {
            if (s + MARGIN > pmin)                ns += exp2f(K_NEG * (s - 0.5f));
        }
    }
#pragma unroll
    for (int m = 32; m; m >>= 1) {
        ps += __shfl_xor(ps, m, 64);
        ns += __shfl_xor(ns, m, 64);
    }
    if ((t & 63) == 0) redsum[t >> 6] = make_float2(ps, ns);
    __syncthreads();
    if (t == 0) {
        ps = redsum[0].x + redsum[1].x + redsum[2].x + redsum[3].x;
        ns = redsum[0].y + redsum[1].y + redsum[2].y + redsum[3].y;
        const float loss = log1pf(ps) * 0.5f + log1pf(ns) * 0.025f;
        atomicAdd(out, loss * (1.0f / (float)B_N));
    }
#undef GET_S
#undef GET_L
}

extern "C" void kernel_launch(void* const* d_in, const int* in_sizes, int n_in,
                              void* d_out, int out_size, void* d_ws, size_t ws_size,
                              hipStream_t stream) {
    const float* feats  = (const float*)d_in[0];
    const float* labels = (const float*)d_in[1];
    float* out = (float*)d_out;

    // ws layout: sim bf16 [4096*4096] = 32 MB | fnorm bf16 = 4 MB | lab u8 = 4 KB
    char* ws = (char*)d_ws;
    ushort_t* Cb   = (ushort_t*)ws;
    ushort_t* fn   = (ushort_t*)(ws + (size_t)B_N * B_N * 2);
    uchar_t*  lab8 = (uchar_t*)(ws + (size_t)B_N * B_N * 2 + (size_t)B_N * DIM * 2);

    prep_kernel<<<B_N, 256, 0, stream>>>(feats, labels, fn, lab8, out);
    dim3 g2(B_N / BM, B_N / BM);
    gemm_sim<<<g2, 256, 0, stream>>>(fn, Cb);
    row_loss_kernel<<<B_N, 256, 0, stream>>>(Cb, lab8, out);
}

// Round 4
// 58.889 us; speedup vs baseline: 2.4237x; 1.6992x over previous
//
#include <hip/hip_runtime.h>
#include <hip/hip_bf16.h>

#define B_N   4096
#define DIM   512
#define NCLS  100
#define MARGIN 0.1f
#define ONE_EPS (1.0f - 1e-5f)
#define K_POS (-2.885390082f)   // -2  * log2(e)
#define K_NEG (57.70780163f)    //  40 * log2(e)
#define BIGF  3.0e38f

typedef __attribute__((ext_vector_type(8))) short short8;   // 8 bf16 = 4 VGPRs (MFMA A/B frag)
typedef __attribute__((ext_vector_type(4))) float f32x4;    // MFMA C/D frag
typedef unsigned short ushort_t;
typedef unsigned char  uchar_t;

__device__ __forceinline__ void async_load16(const void* g, void* l) {
    __builtin_amdgcn_global_load_lds(
        (const __attribute__((address_space(1))) unsigned int*)g,
        (__attribute__((address_space(3))) unsigned int*)l,
        16, 0, 0);
}

__device__ __forceinline__ float blk_sum(float v, float* red) {
#pragma unroll
    for (int m = 32; m; m >>= 1) v += __shfl_xor(v, m, 64);
    const int w = threadIdx.x >> 6;
    if ((threadIdx.x & 63) == 0) red[w] = v;
    __syncthreads();
    v = red[0] + red[1] + red[2] + red[3];
    __syncthreads();
    return v;
}

// ---------- K1: normalize rows -> bf16, one-hot -> u8 index ----------
__global__ __launch_bounds__(256) void prep_kernel(
    const float* __restrict__ feats, const float* __restrict__ labels,
    ushort_t* __restrict__ fn, uchar_t* __restrict__ lab8)
{
    __shared__ float red[4];
    const int r = blockIdx.x, t = threadIdx.x;
    const float v0 = feats[(size_t)r * DIM + t];
    const float v1 = feats[(size_t)r * DIM + t + 256];
    const float ss = blk_sum(v0 * v0 + v1 * v1, red);
    const float sc = rsqrtf(ss);
    __hip_bfloat16 b0 = __float2bfloat16(v0 * sc);
    __hip_bfloat16 b1 = __float2bfloat16(v1 * sc);
    fn[(size_t)r * DIM + t]       = *(ushort_t*)&b0;
    fn[(size_t)r * DIM + t + 256] = *(ushort_t*)&b1;
    if (t < NCLS && labels[(size_t)r * NCLS + t] > 0.5f) lab8[r] = (uchar_t)t;
}

// ---------- K2: sim = F*F^T (bf16 out), full grid, m97 structure ----------
#define BM 128
#define BK 32
#define NKSTEP (DIM / BK)   // 16

__global__ __launch_bounds__(256) void gemm_sim(
    const ushort_t* __restrict__ F, ushort_t* __restrict__ Cb)
{
    __shared__ __align__(16) ushort_t sA[2][BM * BK];
    __shared__ __align__(16) ushort_t sB[2][BM * BK];
    const int t = threadIdx.x;
    const int w = t >> 6, l = t & 63;
    const int brow = blockIdx.y * BM, bcol = blockIdx.x * BM;
    const int wr = w >> 1, wc = w & 1;          // 2x2 waves -> 64x64 each

    const int lr    = l >> 2;
    const int lslot = l & 3;

    f32x4 acc[4][4];
    const f32x4 fz = {0.f, 0.f, 0.f, 0.f};
#pragma unroll
    for (int m = 0; m < 4; ++m)
#pragma unroll
        for (int n = 0; n < 4; ++n) acc[m][n] = fz;

    auto stage = [&](int buf, int kb) {
#pragma unroll
        for (int i = 0; i < 2; ++i) {
            const int c   = w * 2 + i;
            const int row = c * 16 + lr;
            const int kc  = lslot ^ ((row >> 1) & 3);
            async_load16(F + (size_t)(brow + row) * DIM + kb + kc * 8, &sA[buf][c * 512]);
            async_load16(F + (size_t)(bcol + row) * DIM + kb + kc * 8, &sB[buf][c * 512]);
        }
    };

    stage(0, 0);
    __syncthreads();
    int cur = 0;
    for (int ks = 0; ks < NKSTEP; ++ks) {
        if (ks + 1 < NKSTEP) stage(cur ^ 1, (ks + 1) * BK);
        short8 av[4], bv[4];
#pragma unroll
        for (int m = 0; m < 4; ++m) {
            const int r    = wr * 64 + m * 16 + (l & 15);
            const int slot = (l >> 4) ^ ((r >> 1) & 3);
            av[m] = *(const short8*)&sA[cur][r * BK + slot * 8];
        }
#pragma unroll
        for (int n = 0; n < 4; ++n) {
            const int r    = wc * 64 + n * 16 + (l & 15);
            const int slot = (l >> 4) ^ ((r >> 1) & 3);
            bv[n] = *(const short8*)&sB[cur][r * BK + slot * 8];
        }
#pragma unroll
        for (int m = 0; m < 4; ++m)
#pragma unroll
            for (int n = 0; n < 4; ++n)
                acc[m][n] = __builtin_amdgcn_mfma_f32_16x16x32_bf16(av[m], bv[n], acc[m][n], 0, 0, 0);
        __syncthreads();
        cur ^= 1;
    }

    // epilogue: C/D layout col = l&15, row = (l>>4)*4 + r
#pragma unroll
    for (int m = 0; m < 4; ++m) {
        const int row0 = brow + wr * 64 + m * 16 + ((l >> 4) << 2);
#pragma unroll
        for (int n = 0; n < 4; ++n) {
            const int col = bcol + wc * 64 + n * 16 + (l & 15);
            ushort_t* cp = Cb + (size_t)row0 * B_N + col;
#pragma unroll
            for (int r = 0; r < 4; ++r) {
                __hip_bfloat16 hv = __float2bfloat16(acc[m][n][r]);
                cp[(size_t)r * B_N] = *(ushort_t*)&hv;
            }
        }
    }
}

// ---------- K3: per-row mining + loss, one BLOCK per row, NO atomics ----------
__global__ __launch_bounds__(256) void row_loss_kernel(
    const ushort_t* __restrict__ Cb, const uchar_t* __restrict__ lab8,
    float* __restrict__ rowloss)
{
    __shared__ float2 redmm[4];
    __shared__ float2 redsum[4];
    const int i = blockIdx.x, t = threadIdx.x;
    const int li = (int)lab8[i];

    // thread t owns columns j = 16*t + e, e in [0,16)
    const uint4* cb = (const uint4*)(Cb + (size_t)i * B_N);
    uint4 s0 = cb[2 * t];
    uint4 s1 = cb[2 * t + 1];
    uint4 lw = ((const uint4*)lab8)[t];

    // poison diagonal sim -> 2.0 (same-label but fails s < 1-eps; never a neg)
    if ((i >> 4) == t) {
        const int d  = i & 15;
        unsigned* wp = (d < 8) ? (unsigned*)&s0 : (unsigned*)&s1;
        const int dd = d & 7;
        if (dd & 1) wp[dd >> 1] = (wp[dd >> 1] & 0x0000FFFFu) | 0x40000000u;
        else        wp[dd >> 1] = (wp[dd >> 1] & 0xFFFF0000u) | 0x00004000u;
    }

    // pin the row data in registers (prevent per-pass reload/remat)
#define KEEP4(v) asm volatile("" : "+v"(v.x), "+v"(v.y), "+v"(v.z), "+v"(v.w))
    KEEP4(s0); KEEP4(s1); KEEP4(lw);
#undef KEEP4

    const unsigned sw[8] = {s0.x, s0.y, s0.z, s0.w, s1.x, s1.y, s1.z, s1.w};
    const unsigned lwd[4] = {lw.x, lw.y, lw.z, lw.w};

#define GET_S(e)  __uint_as_float(((e) & 1) ? (sw[(e) >> 1] & 0xFFFF0000u) : (sw[(e) >> 1] << 16))
#define GET_L(e)  ((int)((lwd[(e) >> 2] >> (((e) & 3) * 8)) & 0xFFu))

    // pass 1: pos_min (valid positives) and global neg max, together
    float pmin = BIGF, ngmax = -BIGF;
#pragma unroll
    for (int e = 0; e < 16; ++e) {
        const float s = GET_S(e);
        const int lbl = GET_L(e);
        if (lbl == li) { if (s < ONE_EPS) pmin = fminf(pmin, s); }
        else           ngmax = fmaxf(ngmax, s);
    }
#pragma unroll
    for (int m = 32; m; m >>= 1) {
        pmin  = fminf(pmin,  __shfl_xor(pmin,  m, 64));
        ngmax = fmaxf(ngmax, __shfl_xor(ngmax, m, 64));
    }
    if ((t & 63) == 0) redmm[t >> 6] = make_float2(pmin, ngmax);
    __syncthreads();
    pmin  = fminf(fminf(redmm[0].x, redmm[1].x), fminf(redmm[2].x, redmm[3].x));
    ngmax = fmaxf(fmaxf(redmm[0].y, redmm[1].y), fmaxf(redmm[2].y, redmm[3].y));

    // closed-form mining:
    //   any neg kept  <=> ngmax + margin > pmin  (then neg_max = ngmax)
    //   any pos kept  <=> pmin - margin < neg_max
    const bool anyneg = (ngmax + MARGIN > pmin);
    const float nmax  = anyneg ? ngmax : -BIGF;
    const bool valid  = anyneg && (pmin - MARGIN < nmax);
    if (!valid) {                 // uniform across block
        if (t == 0) rowloss[i] = 0.0f;
        return;
    }

    // pass 2: both exp-sums in one sweep
    float ps = 0.f, ns = 0.f;
#pragma unroll
    for (int e = 0; e < 16; ++e) {
        const float s = GET_S(e);
        const int lbl = GET_L(e);
        if (lbl == li) {
            if (s < ONE_EPS && s - MARGIN < nmax) ps += exp2f(K_POS * (s - 0.5f));
        } else {
            if (s + MARGIN > pmin)                ns += exp2f(K_NEG * (s - 0.5f));
        }
    }
#pragma unroll
    for (int m = 32; m; m >>= 1) {
        ps += __shfl_xor(ps, m, 64);
        ns += __shfl_xor(ns, m, 64);
    }
    if ((t & 63) == 0) redsum[t >> 6] = make_float2(ps, ns);
    __syncthreads();
    if (t == 0) {
        ps = redsum[0].x + redsum[1].x + redsum[2].x + redsum[3].x;
        ns = redsum[0].y + redsum[1].y + redsum[2].y + redsum[3].y;
        rowloss[i] = log1pf(ps) * 0.5f + log1pf(ns) * 0.025f;
    }
#undef GET_S
#undef GET_L
}

// ---------- K4: sum rowloss -> out[0] (single block, no atomics) ----------
__global__ __launch_bounds__(256) void final_reduce(
    const float* __restrict__ rowloss, float* __restrict__ out)
{
    __shared__ float red[4];
    const int t = threadIdx.x;
    const float4* rp = (const float4*)rowloss;
    float v = 0.f;
#pragma unroll
    for (int q = 0; q < 4; ++q) {
        const float4 a = rp[t + 256 * q];
        v += (a.x + a.y) + (a.z + a.w);
    }
    v = blk_sum(v, red);
    if (t == 0) out[0] = v * (1.0f / (float)B_N);
}

extern "C" void kernel_launch(void* const* d_in, const int* in_sizes, int n_in,
                              void* d_out, int out_size, void* d_ws, size_t ws_size,
                              hipStream_t stream) {
    const float* feats  = (const float*)d_in[0];
    const float* labels = (const float*)d_in[1];
    float* out = (float*)d_out;

    // ws: sim bf16 32MB | fnorm bf16 4MB | lab u8 4KB | rowloss f32 16KB
    char* ws = (char*)d_ws;
    ushort_t* Cb   = (ushort_t*)ws;
    ushort_t* fn   = (ushort_t*)(ws + (size_t)B_N * B_N * 2);
    uchar_t*  lab8 = (uchar_t*)(ws + (size_t)B_N * B_N * 2 + (size_t)B_N * DIM * 2);
    float* rowloss = (float*)(ws + (size_t)B_N * B_N * 2 + (size_t)B_N * DIM * 2 + (size_t)B_N);

    prep_kernel<<<B_N, 256, 0, stream>>>(feats, labels, fn, lab8);
    dim3 g2(B_N / BM, B_N / BM);
    gemm_sim<<<g2, 256, 0, stream>>>(fn, Cb);
    row_loss_kernel<<<B_N, 256, 0, stream>>>(Cb, lab8, rowloss);
    final_reduce<<<1, 256, 0, stream>>>(rowloss, out);
}